// Round 14
// baseline (298.601 us; speedup 1.0000x reference)
//
#include <hip/hip_runtime.h>
#include <hip/hip_bf16.h>
#include <cstdint>
#include <cstddef>

// ---------------------------------------------------------------------------
// LSTM cell: ht = sigmoid(o) * tanh(sigmoid(f)*c + sigmoid(i)*sigmoid(c~))
// gates = [prev_state, x] @ W'^T with W' row-interleaved: W'[4h+g] = W_g[h].
// Cell update fused into GEMM epilogue (gates never touch HBM).
// GEMM core: 256x256, BK=64, round-11 schedule (8 regions/2 K-tiles, BAR
// every 2nd region, vmcnt(4) certs at r4/r8) — UNCHANGED skeleton.
// THIS ROUND: 16x16x32 -> 32x32x16 MFMA (m119: 2495 vs 2176 TF ceiling).
// Same LDS traffic (8+4 b128 reads/region), half the MFMA instructions.
// Fragments: A row=lane&31, k-chunk (s*2+(lane>>5))^(lane&7); B-half Y=cb,
// LDS row wc*32+(lane&31); C/D col=lane&31,row=(q&3)+8*(q>>2)+4*(lane>>5).
// ---------------------------------------------------------------------------

typedef __bf16 nbf16;
typedef nbf16 bf16x8 __attribute__((ext_vector_type(8)));
typedef float f32x16 __attribute__((ext_vector_type(16)));

static constexpr int MDIM = 4096;
static constexpr int NDIM = 8192;
static constexpr int KDIM = 4096;
static constexpr int HDIM = 2048;
static constexpr int KB   = KDIM * 2;     // K row stride in bytes

#define VMW4  asm volatile("s_waitcnt vmcnt(4)" ::: "memory")
#define VMW0  asm volatile("s_waitcnt vmcnt(0)" ::: "memory")
#define LGKM0 asm volatile("s_waitcnt lgkmcnt(0)" ::: "memory")
#define BAR   __builtin_amdgcn_s_barrier()
#define SB0   __builtin_amdgcn_sched_barrier(0)
#define PRIO1 __builtin_amdgcn_s_setprio(1)
#define PRIO0 __builtin_amdgcn_s_setprio(0)

__device__ __forceinline__ void async16(void* lds, const void* g) {
    __builtin_amdgcn_global_load_lds(
        (const __attribute__((address_space(1))) void*)g,
        (__attribute__((address_space(3))) void*)lds,
        16, 0, 0);
}

__device__ __forceinline__ float fsig(float x) {
    return __builtin_amdgcn_rcpf(1.0f + __expf(-x));
}
__device__ __forceinline__ float ftanh(float x) {
    return 2.0f * __builtin_amdgcn_rcpf(1.0f + __expf(-2.0f * x)) - 1.0f;
}

// LDS half = 128 rows x 64 k bf16 = 16 KB; stored chunk = logical ^ (row&7),
// realized as linear LDS dest + inverse-permuted global source (rule 21).
__device__ __forceinline__ void stage_A(const char* Ab, int X, int t, char* slot,
                                        int wave, int r0, int cb) {
    const char* s = Ab + (size_t)(X * 64 + r0) * KB + t * 128 + cb;
    async16(slot + wave * 1024, s);
    async16(slot + (wave + 8) * 1024, s + (size_t)128 * KB);
}
__device__ __forceinline__ void stage_B(const char* Wb, int Y, int t, char* slot,
                                        int wave, int rB0, int cb) {
    const char* s = Wb + (size_t)(rB0 + Y * 32) * KB + t * 128 + cb;
    async16(slot + wave * 1024, s);
    async16(slot + (wave + 8) * 1024, s + (size_t)128 * KB);
}

// A frags for one half: d[rb][s], rb = 32-row block, s = 16-k slice.
__device__ __forceinline__ void read_A32(bf16x8 (&d)[2][4], const char* hb,
                                         int arow, const int* kc) {
#pragma unroll
    for (int rb = 0; rb < 2; ++rb)
#pragma unroll
        for (int s = 0; s < 4; ++s)
            d[rb][s] = *(const bf16x8*)(hb + arow + rb * 4096 + kc[s]);
}
// B frags for one half (one 32-col block): d[s]
__device__ __forceinline__ void read_B32(bf16x8 (&d)[4], const char* hb,
                                         int brow, const int* kc) {
#pragma unroll
    for (int s = 0; s < 4; ++s)
        d[s] = *(const bf16x8*)(hb + brow + kc[s]);
}
__device__ __forceinline__ void mfma32(f32x16 (&acc)[4][2], int mh, int cb,
                                       const bf16x8 (&a)[2][4],
                                       const bf16x8 (&b)[4]) {
#pragma unroll
    for (int s = 0; s < 4; ++s)
#pragma unroll
        for (int rb = 0; rb < 2; ++rb)
            acc[mh * 2 + rb][cb] = __builtin_amdgcn_mfma_f32_32x32x16_bf16(
                a[rb][s], b[s], acc[mh * 2 + rb][cb], 0, 0, 0);
}

// ---- concat(prev_state, x) -> bf16 A [MDIM][KDIM] -------------------------
__global__ __launch_bounds__(256) void k_concat_cast(
        const float* __restrict__ prev, const float* __restrict__ x,
        __hip_bfloat16* __restrict__ A) {
    const size_t total8 = (size_t)MDIM * KDIM / 8;
    const size_t stride = (size_t)gridDim.x * blockDim.x;
    for (size_t i = (size_t)blockIdx.x * blockDim.x + threadIdx.x; i < total8;
         i += stride) {
        size_t e = i * 8;
        size_t b = e >> 12;
        int k = (int)(e & (KDIM - 1));
        const float* src = (k < HDIM) ? (prev + b * HDIM + k)
                                      : (x + b * HDIM + (k - HDIM));
        float4 v0 = *(const float4*)src;
        float4 v1 = *(const float4*)(src + 4);
        union { __hip_bfloat16 h[8]; int4 q; } u;
        u.h[0] = __float2bfloat16(v0.x); u.h[1] = __float2bfloat16(v0.y);
        u.h[2] = __float2bfloat16(v0.z); u.h[3] = __float2bfloat16(v0.w);
        u.h[4] = __float2bfloat16(v1.x); u.h[5] = __float2bfloat16(v1.y);
        u.h[6] = __float2bfloat16(v1.z); u.h[7] = __float2bfloat16(v1.w);
        *(int4*)(A + e) = u.q;
    }
}

// ---- gate-interleaved W': row n = W_{n&3}[n>>2], bf16 [NDIM][KDIM] ---------
__global__ __launch_bounds__(256) void k_cast_w(
        const float* __restrict__ w0, const float* __restrict__ w1,
        const float* __restrict__ w2, const float* __restrict__ w3,
        __hip_bfloat16* __restrict__ W) {
    const size_t total8 = (size_t)NDIM * KDIM / 8;
    const size_t stride = (size_t)gridDim.x * blockDim.x;
    for (size_t i = (size_t)blockIdx.x * blockDim.x + threadIdx.x; i < total8;
         i += stride) {
        size_t e = i * 8;
        int n = (int)(e >> 12);
        int k = (int)(e & (KDIM - 1));
        int g = n & 3;
        size_t h = (size_t)(n >> 2);
        const float* src = (g == 0 ? w0 : g == 1 ? w1 : g == 2 ? w2 : w3)
                           + h * KDIM + k;
        float4 v0 = *(const float4*)src;
        float4 v1 = *(const float4*)(src + 4);
        union { __hip_bfloat16 h[8]; int4 q; } u;
        u.h[0] = __float2bfloat16(v0.x); u.h[1] = __float2bfloat16(v0.y);
        u.h[2] = __float2bfloat16(v0.z); u.h[3] = __float2bfloat16(v0.w);
        u.h[4] = __float2bfloat16(v1.x); u.h[5] = __float2bfloat16(v1.y);
        u.h[6] = __float2bfloat16(v1.z); u.h[7] = __float2bfloat16(v1.w);
        *(int4*)(W + e) = u.q;
    }
}

// ---- GEMM + fused LSTM cell epilogue ---------------------------------------
__global__ __launch_bounds__(512, 2) void k_gemm(
        const __hip_bfloat16* __restrict__ A, const __hip_bfloat16* __restrict__ W,
        const float* __restrict__ c, float* __restrict__ out) {
    __shared__ __align__(16) char lds[131072];

    // 2-D XCD swizzle: XCD (bid&7) owns an 8(mt) x 8(nt) sub-grid (bijective)
    const int bid = blockIdx.x;
    const int xcd = bid & 7, j = bid >> 3;
    const int mt = (xcd >> 2) * 8 + (j >> 3);
    const int nt = (xcd & 3) * 8 + (j & 7);
    const int brow = mt * 256, bcol = nt * 256;

    const int tid = threadIdx.x;
    const int wave = tid >> 6, lane = tid & 63;
    const int wr = wave >> 2, wc = wave & 3;

    const char* Ab = (const char*)A + (size_t)brow * KB;
    const char* Wb = (const char*)W + (size_t)bcol * KB;

    char* const Ah00 = lds;
    char* const Ah01 = lds + 16384;
    char* const Ah10 = lds + 32768;
    char* const Ah11 = lds + 49152;
    char* const Bh00 = lds + 65536;
    char* const Bh01 = lds + 81920;
    char* const Bh10 = lds + 98304;
    char* const Bh11 = lds + 114688;

    const int r0  = wave * 8 + (lane >> 3);
    const int rB0 = ((r0 >> 5) << 6) + (r0 & 31);
    const int cb  = (((lane & 7) ^ (lane >> 3)) << 4);
    // 32x32 fragment constants
    const int arow = (wr * 64 + (lane & 31)) * 128;
    const int brow32 = (wc * 32 + (lane & 31)) * 128;
    const int g32 = lane >> 5;
    const int kc[4] = {
        (((0 * 2 + g32) ^ (lane & 7)) << 4),
        (((1 * 2 + g32) ^ (lane & 7)) << 4),
        (((2 * 2 + g32) ^ (lane & 7)) << 4),
        (((3 * 2 + g32) ^ (lane & 7)) << 4)};

    f32x16 acc32[4][2] = {};
    bf16x8 a0[2][4], a1[2][4], b0[4], b1[4];

    // ---- prologue: stage tiles 0 (s0) and 1 (s1) ----
    stage_B(Wb, 0, 0, Bh00, wave, rB0, cb);
    stage_A(Ab, 0, 0, Ah00, wave, r0, cb);
    stage_A(Ab, 1, 0, Ah01, wave, r0, cb);
    stage_B(Wb, 1, 0, Bh01, wave, rB0, cb);
    stage_B(Wb, 0, 1, Bh10, wave, rB0, cb);
    stage_A(Ab, 0, 1, Ah10, wave, r0, cb);
    stage_A(Ab, 1, 1, Ah11, wave, r0, cb);
    stage_B(Wb, 1, 1, Bh11, wave, rB0, cb);
    VMW4;                     // certify first 12 gll (through Ah10)
    SB0; BAR;
    read_A32(a0, Ah00, arow, kc);
    read_B32(b0, Bh00, brow32, kc);
    LGKM0;                    // drain pre-loop reads before r1 restages Bh00
    SB0; BAR;                 // even boundary anchoring the loop period

    // ---- main loop: 32 iters x 2 K-tiles; 8 regions; BAR every 2nd region;
    //      stage-certify vmcnt(4) only at ends of r4 and r8 ----
    for (int i = 0; i < 32; ++i) {
        const int t2 = (2 * i + 2) & 63;
        const int t3 = (2 * i + 3) & 63;

        // r1 (odd): reads A-hi(s0)->a1; stage B-lo(s0,t2); MFMA (0,0)[a0,b0]
        read_A32(a1, Ah01, arow, kc);
        stage_B(Wb, 0, t2, Bh00, wave, rB0, cb);
        SB0;
        PRIO1; mfma32(acc32, 0, 0, a0, b0); PRIO0;
        LGKM0; SB0;
        // r2 (even, BAR): reads B-hi(s0)->b1; stage A-lo(s0,t2); MFMA (1,0)[a1,b0]
        read_B32(b1, Bh01, brow32, kc);
        stage_A(Ab, 0, t2, Ah00, wave, r0, cb);
        SB0;
        PRIO1; mfma32(acc32, 1, 0, a1, b0); PRIO0;
        LGKM0; SB0; BAR;
        // r3 (odd): reads B-lo(s1)->b0; stage A-hi(s0,t2); MFMA (1,1)[a1,b1]
        read_B32(b0, Bh10, brow32, kc);
        stage_A(Ab, 1, t2, Ah01, wave, r0, cb);
        SB0;
        PRIO1; mfma32(acc32, 1, 1, a1, b1); PRIO0;
        LGKM0; SB0;
        // r4 (even, VMW4+BAR): reads A-lo(s1)->a1; stage B-hi(s0,t2); MFMA (0,1)[a0,b1]
        read_A32(a1, Ah10, arow, kc);
        stage_B(Wb, 1, t2, Bh01, wave, rB0, cb);
        SB0;
        PRIO1; mfma32(acc32, 0, 1, a0, b1); PRIO0;
        LGKM0; VMW4; SB0; BAR;
        // r5 (odd): reads A-hi(s1)->a0; stage B-lo(s1,t3); MFMA (0,0)[a1,b0]
        read_A32(a0, Ah11, arow, kc);
        stage_B(Wb, 0, t3, Bh10, wave, rB0, cb);
        SB0;
        PRIO1; mfma32(acc32, 0, 0, a1, b0); PRIO0;
        LGKM0; SB0;
        // r6 (even, BAR): reads B-hi(s1)->b1; stage A-lo(s1,t3); MFMA (1,0)[a0,b0]
        read_B32(b1, Bh11, brow32, kc);
        stage_A(Ab, 0, t3, Ah10, wave, r0, cb);
        SB0;
        PRIO1; mfma32(acc32, 1, 0, a0, b0); PRIO0;
        LGKM0; SB0; BAR;
        // r7 (odd): reads B-lo(s0,t2)->b0; stage A-hi(s1,t3); MFMA (1,1)[a0,b1]
        read_B32(b0, Bh00, brow32, kc);
        stage_A(Ab, 1, t3, Ah11, wave, r0, cb);
        SB0;
        PRIO1; mfma32(acc32, 1, 1, a0, b1); PRIO0;
        LGKM0; SB0;
        // r8 (even, VMW4+BAR): reads A-lo(s0,t2)->a0; stage B-hi(s1,t3); MFMA (0,1)[a1,b1]
        read_A32(a0, Ah00, arow, kc);
        stage_B(Wb, 1, t3, Bh11, wave, rB0, cb);
        SB0;
        PRIO1; mfma32(acc32, 0, 1, a1, b1); PRIO0;
        LGKM0; VMW4; SB0; BAR;
    }

    // ---- fused cell epilogue: single pass through 128 KB LDS C-tile ----
    VMW0; LGKM0;
    BAR;
    __hip_bfloat16* cl = (__hip_bfloat16*)lds;      // [256][256] bf16 = 128 KB
    const int h0 = bcol >> 2;
    {
        // C/D: col = lane&31, row = (q&3) + 8*(q>>2) + 4*(lane>>5)
        const int erow = wr * 128 + 4 * g32;
        const int ecol = wc * 64 + (lane & 31);
        #pragma unroll
        for (int rbg = 0; rbg < 4; ++rbg)
            #pragma unroll
            for (int cbk = 0; cbk < 2; ++cbk)
                #pragma unroll
                for (int q = 0; q < 16; ++q)
                    cl[(erow + rbg * 32 + (q & 3) + 8 * (q >> 2)) * 256 +
                       (ecol + cbk * 32)] =
                        __float2bfloat16(acc32[rbg][cbk][q]);
    }
    BAR;
    #pragma unroll
    for (int rnd = 0; rnd < 8; ++rnd) {
        const int row = rnd * 32 + (tid >> 4);
        const int ccol = (tid & 15) * 16;
        union { int4 q[2]; __hip_bfloat16 h[16]; } v;
        v.q[0] = *(const int4*)&cl[row * 256 + ccol];
        v.q[1] = *(const int4*)&cl[row * 256 + ccol + 8];
        const size_t R = (size_t)(brow + row);
        const int hh = h0 + (tid & 15) * 4;
        float4 cc = *(const float4*)(c + R * HDIM + hh);
        float cs[4] = {cc.x, cc.y, cc.z, cc.w};
        float ht[4];
        #pragma unroll
        for (int u = 0; u < 4; ++u) {
            float ft  = fsig(__bfloat162float(v.h[4 * u + 0]));
            float it  = fsig(__bfloat162float(v.h[4 * u + 1]));
            float ctt = fsig(__bfloat162float(v.h[4 * u + 2]));
            float ot  = fsig(__bfloat162float(v.h[4 * u + 3]));
            float ct  = ft * cs[u] + it * ctt;
            ht[u] = ot * ftanh(ct);
        }
        float4 o = {ht[0], ht[1], ht[2], ht[3]};
        *(float4*)(out + R * HDIM + hh) = o;
    }
}

extern "C" void kernel_launch(void* const* d_in, const int* in_sizes, int n_in,
                              void* d_out, int out_size, void* d_ws, size_t ws_size,
                              hipStream_t stream) {
    const float* x    = (const float*)d_in[0];
    const float* prev = (const float*)d_in[1];
    const float* cst  = (const float*)d_in[2];
    const float* wfg  = (const float*)d_in[3];
    const float* wig  = (const float*)d_in[4];
    const float* wog  = (const float*)d_in[5];
    const float* wol  = (const float*)d_in[6];
    float* out = (float*)d_out;

    char* ws = (char*)d_ws;
    __hip_bfloat16* Abf = (__hip_bfloat16*)(ws);                 // 32 MB
    __hip_bfloat16* Wbf = (__hip_bfloat16*)(ws + 33554432);      // 64 MB

    k_concat_cast<<<2048, 256, 0, stream>>>(prev, x, Abf);
    k_cast_w<<<2048, 256, 0, stream>>>(wfg, wig, wog, wol, Wbf);
    k_gemm<<<512, 512, 0, stream>>>(Abf, Wbf, cst, out);
}